// Round 2
// baseline (225.215 us; speedup 1.0000x reference)
//
#include <hip/hip_runtime.h>
#include <hip/hip_bf16.h>

typedef __attribute__((ext_vector_type(8))) short short8;
typedef __attribute__((ext_vector_type(4))) float f32x4;

#define MFMA16(a, b, c) __builtin_amdgcn_mfma_f32_16x16x32_bf16((a), (b), (c), 0, 0, 0)

// sizes: B=16, C=256, N=1024 (32x32), HEADS=4, DHEAD=64, HID=256, OTOT=768

__device__ __forceinline__ ushort f2bf(float f) {
  union { float f; unsigned u; } x; x.f = f;
  unsigned r = x.u + 0x7FFFu + ((x.u >> 16) & 1u);
  return (ushort)(r >> 16);
}

__device__ __forceinline__ float bf2f(ushort u) {
  union { unsigned u; float f; } x; x.u = ((unsigned)u) << 16;
  return x.f;
}

__device__ __forceinline__ short8 ld8(const ushort* p) {
  return *reinterpret_cast<const short8*>(p);
}

// ---------------- kernel 0a: transpose + convert x,y (b,c,n)f32 -> (b,n,c)bf16
__global__ __launch_bounds__(256) void k_tcvt(const float* __restrict__ x,
    const float* __restrict__ y, ushort* __restrict__ xbt, ushort* __restrict__ ybt) {
  int tile = blockIdx.x;
  const float* src; ushort* dst;
  if (tile >= 1024) { tile -= 1024; src = y; dst = ybt; }
  else { src = x; dst = xbt; }
  int b = tile >> 6;
  int c0 = ((tile >> 4) & 3) << 6;
  int n0 = (tile & 15) << 6;
  __shared__ ushort lds[64][65];
  int tid = threadIdx.x;
  int nl = tid & 63, cl = tid >> 6;
  const float* sb = src + ((size_t)b << 18);
#pragma unroll
  for (int s = 0; s < 16; ++s) {
    int c = cl + (s << 2);
    lds[c][nl] = f2bf(sb[(size_t)(c0 + c) * 1024 + n0 + nl]);
  }
  __syncthreads();
  ushort* db = dst + ((size_t)b << 18);
  int cl2 = tid & 63, nl2 = tid >> 6;
#pragma unroll
  for (int s = 0; s < 16; ++s) {
    int n = nl2 + (s << 2);
    db[(size_t)(n0 + n) * 256 + c0 + cl2] = lds[cl2][n];
  }
}

// ---------------- kernel 0b: convert weights to bf16 (same layout, [o][c])
__global__ __launch_bounds__(256) void k_wcvt(const float* __restrict__ wqkv,
    const float* __restrict__ wout, ushort* __restrict__ wqkvb, ushort* __restrict__ woutb) {
  const int total1 = 768 * 256;
  const int total = total1 + 256 * 256;
  for (int i = blockIdx.x * 256 + threadIdx.x; i < total; i += gridDim.x * 256) {
    if (i < total1) wqkvb[i] = f2bf(wqkv[i]);
    else woutb[i - total1] = f2bf(wout[i - total1]);
  }
}

// ---------------- kernel 1: QKV projection GEMM + row sum-of-squares
// grid (24, 16): o-tile 32 rows, all 1024 n. 512 threads = 8 waves, wave: 32o x 128n.
__global__ __launch_bounds__(512) void k_qkv(const ushort* __restrict__ wqkvb,
    const ushort* __restrict__ xbt, const ushort* __restrict__ ybt,
    ushort* __restrict__ qraw, ushort* __restrict__ kraw,
    ushort* __restrict__ vbuf, float* __restrict__ norms) {
  int o0 = blockIdx.x * 32;
  int b = blockIdx.y;
  const ushort* Bsrc = (o0 < 256) ? xbt : ybt;   // q from x; k,v from y
  const ushort* Bm = Bsrc + ((size_t)b << 18);
  int tid = threadIdx.x;
  int l = tid & 63, w = tid >> 6;
  int r = l & 15, g = l >> 4;
  const ushort* Ab = wqkvb + (size_t)(o0 + r) * 256 + g * 8;
  const ushort* Bb = Bm + (size_t)(w * 128 + r) * 256 + g * 8;
  f32x4 acc[2][8];
#pragma unroll
  for (int i = 0; i < 2; ++i)
#pragma unroll
    for (int j = 0; j < 8; ++j) acc[i][j] = (f32x4){0.f, 0.f, 0.f, 0.f};
#pragma unroll
  for (int ks = 0; ks < 8; ++ks) {
    short8 a0 = ld8(Ab + ks * 32);
    short8 a1 = ld8(Ab + 4096 + ks * 32);
#pragma unroll
    for (int nf = 0; nf < 8; ++nf) {
      short8 bv = ld8(Bb + (size_t)nf * 4096 + ks * 32);
      acc[0][nf] = MFMA16(a0, bv, acc[0][nf]);
      acc[1][nf] = MFMA16(a1, bv, acc[1][nf]);
    }
  }
  // row sum-of-squares for q,k (l2norm is over n; rows fully inside this block)
  __shared__ float snorm[8][32];
  if (o0 < 512) {
    float ss[2][4];
#pragma unroll
    for (int mf = 0; mf < 2; ++mf)
#pragma unroll
      for (int reg = 0; reg < 4; ++reg) {
        float s = 0.f;
#pragma unroll
        for (int nf = 0; nf < 8; ++nf) { float v = acc[mf][nf][reg]; s += v * v; }
#pragma unroll
        for (int m = 1; m < 16; m <<= 1) s += __shfl_xor(s, m);
        ss[mf][reg] = s;
      }
    if (r == 0) {
#pragma unroll
      for (int mf = 0; mf < 2; ++mf)
#pragma unroll
        for (int reg = 0; reg < 4; ++reg)
          snorm[w][mf * 16 + g * 4 + reg] = ss[mf][reg];
    }
    __syncthreads();
    if (tid < 32) {
      float s = 0.f;
#pragma unroll
      for (int w2 = 0; w2 < 8; ++w2) s += snorm[w2][tid];
      norms[b * 512 + o0 + tid] = s;
    }
  }
  // store raw q,k and v as bf16, [b][256][1024] each
#pragma unroll
  for (int mf = 0; mf < 2; ++mf) {
    int ob = o0 + mf * 16 + g * 4;
#pragma unroll
    for (int nf = 0; nf < 8; ++nf) {
      int n = w * 128 + nf * 16 + r;
#pragma unroll
      for (int reg = 0; reg < 4; ++reg) {
        ushort v = f2bf(acc[mf][nf][reg]);
        int oo = ob + reg;
        if (o0 < 256)       qraw[(((size_t)b * 256 + oo) << 10) + n] = v;
        else if (o0 < 512)  kraw[(((size_t)b * 256 + (oo - 256)) << 10) + n] = v;
        else                vbuf[(((size_t)b * 256 + (oo - 512)) << 10) + n] = v;
      }
    }
  }
}

// ---------------- kernel 1b: scale by 1/norm (SCALE folded into q) + transpose to [n][d] bf16
__global__ __launch_bounds__(256) void k_normt(const ushort* __restrict__ qraw,
    const ushort* __restrict__ kraw, const float* __restrict__ norms,
    ushort* __restrict__ qt, ushort* __restrict__ kt) {
  int tile = blockIdx.x;
  const ushort* src; ushort* dst; int which;
  if (tile >= 1024) { tile -= 1024; src = kraw; dst = kt; which = 1; }
  else { src = qraw; dst = qt; which = 0; }
  int b = tile >> 6;
  int h = (tile >> 4) & 3;
  int n0 = (tile & 15) << 6;
  __shared__ ushort lds[64][65];
  __shared__ float fs[64];
  int tid = threadIdx.x;
  if (tid < 64) {
    float ss = norms[b * 512 + which * 256 + h * 64 + tid];
    fs[tid] = (which ? 1.0f : 10.0f) / fmaxf(sqrtf(ss), 1e-12f);
  }
  __syncthreads();
  const ushort* sb = src + (((size_t)b * 256 + h * 64) << 10);
  int nl = tid & 63, dl = tid >> 6;
#pragma unroll
  for (int s = 0; s < 16; ++s) {
    int d = dl + (s << 2);
    lds[d][nl] = f2bf(bf2f(sb[((size_t)d << 10) + n0 + nl]) * fs[d]);
  }
  __syncthreads();
  ushort* db = dst + (((size_t)(b * 4 + h) << 10) + n0) * 64;
  int dl2 = tid & 63, nl2 = tid >> 6;
#pragma unroll
  for (int s = 0; s < 16; ++s) {
    int n = nl2 + (s << 2);
    db[(size_t)n * 64 + dl2] = lds[dl2][n];
  }
}

// ---------------- kernel 2: fused attention (no-max softmax, unnormalized accumulate)
// grid (8 i-tiles, 4 heads, 16 batch), 256 thr = 4 waves; wave owns 32 q-rows.
__global__ __launch_bounds__(256) void k_attn(const ushort* __restrict__ qt,
    const ushort* __restrict__ kt, const ushort* __restrict__ vbuf,
    ushort* __restrict__ aot) {
  int it = blockIdx.x, h = blockIdx.y, b = blockIdx.z;
  int tid = threadIdx.x;
  int l = tid & 63, w = tid >> 6;
  int r = l & 15, g = l >> 4;
  size_t ho = ((size_t)(b * 4 + h)) << 16;
  const ushort* Q = qt + ho;      // [n][64]
  const ushort* K = kt + ho;      // [n][64]
  const ushort* V = vbuf + ((size_t)b << 18) + ((size_t)h << 16);  // [d][n]
  int i0 = it * 128 + w * 32;
  short8 qa[2][2];
#pragma unroll
  for (int mf = 0; mf < 2; ++mf)
#pragma unroll
    for (int ks = 0; ks < 2; ++ks)
      qa[mf][ks] = ld8(Q + (size_t)(i0 + mf * 16 + r) * 64 + ks * 32 + g * 8);
  f32x4 oacc[2][4];
  float rsum[2][4];
#pragma unroll
  for (int mf = 0; mf < 2; ++mf)
#pragma unroll
    for (int j = 0; j < 4; ++j) { oacc[mf][j] = (f32x4){0.f, 0.f, 0.f, 0.f}; rsum[mf][j] = 0.f; }
  __shared__ __align__(16) ushort plds[4][2048];  // per-wave 32x64 bf16, XOR-swizzled
  char* plc = (char*)plds[w];
  for (int j0 = 0; j0 < 1024; j0 += 64) {
    f32x4 sacc[2][4];
#pragma unroll
    for (int mf = 0; mf < 2; ++mf)
#pragma unroll
      for (int nf = 0; nf < 4; ++nf) sacc[mf][nf] = (f32x4){0.f, 0.f, 0.f, 0.f};
#pragma unroll
    for (int nf = 0; nf < 4; ++nf) {
      short8 k0 = ld8(K + (size_t)(j0 + nf * 16 + r) * 64 + g * 8);
      short8 k1 = ld8(K + (size_t)(j0 + nf * 16 + r) * 64 + 32 + g * 8);
      sacc[0][nf] = MFMA16(qa[0][0], k0, sacc[0][nf]);
      sacc[0][nf] = MFMA16(qa[0][1], k1, sacc[0][nf]);
      sacc[1][nf] = MFMA16(qa[1][0], k0, sacc[1][nf]);
      sacc[1][nf] = MFMA16(qa[1][1], k1, sacc[1][nf]);
    }
    // P = exp(S); accumulate row sums; write P to per-wave LDS (swizzled).
    // bf16 truncation (not RTN): the truncation bias is common to numerator
    // and row-sum denominator, so it cancels in the softmax ratio.
#pragma unroll
    for (int mf = 0; mf < 2; ++mf)
#pragma unroll
      for (int nf = 0; nf < 4; ++nf)
#pragma unroll
        for (int reg = 0; reg < 4; ++reg) {
          float p = __expf(sacc[mf][nf][reg]);
          rsum[mf][reg] += p;
          union { float f; unsigned u; } cv; cv.f = p;
          int row = mf * 16 + g * 4 + reg;
          int xorv = ((row ^ (row >> 3)) & 7) << 4;
          int byteo = row * 128 + (((nf * 16 + r) * 2) ^ xorv);
          *(ushort*)(plc + byteo) = (ushort)(cv.u >> 16);
        }
    // read back as A-fragments
    short8 pa[2][2];
#pragma unroll
    for (int mf = 0; mf < 2; ++mf)
#pragma unroll
      for (int ks = 0; ks < 2; ++ks) {
        int row = mf * 16 + r;
        int xorv = (row ^ (row >> 3)) & 7;
        int blk = (ks * 4 + g) ^ xorv;
        pa[mf][ks] = *reinterpret_cast<const short8*>(plc + row * 128 + blk * 16);
      }
    // O += P * V^T
#pragma unroll
    for (int df = 0; df < 4; ++df) {
#pragma unroll
      for (int ks = 0; ks < 2; ++ks) {
        short8 vf = ld8(V + (size_t)(df * 16 + r) * 1024 + j0 + ks * 32 + g * 8);
        oacc[0][df] = MFMA16(pa[0][ks], vf, oacc[0][df]);
        oacc[1][df] = MFMA16(pa[1][ks], vf, oacc[1][df]);
      }
    }
  }
  // finalize: divide by row sums, store attention output transposed [n][hid] bf16
#pragma unroll
  for (int mf = 0; mf < 2; ++mf)
#pragma unroll
    for (int reg = 0; reg < 4; ++reg) {
      float s = rsum[mf][reg];
#pragma unroll
      for (int m = 1; m < 16; m <<= 1) s += __shfl_xor(s, m);
      rsum[mf][reg] = 1.0f / s;
    }
#pragma unroll
  for (int mf = 0; mf < 2; ++mf)
#pragma unroll
    for (int df = 0; df < 4; ++df)
#pragma unroll
      for (int reg = 0; reg < 4; ++reg) {
        int i = i0 + mf * 16 + g * 4 + reg;
        int d = df * 16 + r;
        float vo = oacc[mf][df][reg] * rsum[mf][reg];
        aot[((size_t)b << 18) + (size_t)i * 256 + h * 64 + d] = f2bf(vo);
      }
}

// ---------------- kernel 3: output projection + bias
// grid (16, 16): o-tile 16 rows, all 1024 n. 512 thr = 8 waves, wave: 16o x 128n.
__global__ __launch_bounds__(512) void k_out(const ushort* __restrict__ woutb,
    const ushort* __restrict__ aot, const float* __restrict__ bout,
    float* __restrict__ out) {
  int o0 = blockIdx.x * 16, b = blockIdx.y;
  int tid = threadIdx.x, l = tid & 63, w = tid >> 6, r = l & 15, g = l >> 4;
  const ushort* Ab = woutb + (size_t)(o0 + r) * 256 + g * 8;
  const ushort* Bb = aot + ((size_t)b << 18) + (size_t)(w * 128 + r) * 256 + g * 8;
  f32x4 acc[8];
#pragma unroll
  for (int j = 0; j < 8; ++j) acc[j] = (f32x4){0.f, 0.f, 0.f, 0.f};
#pragma unroll
  for (int ks = 0; ks < 8; ++ks) {
    short8 a0 = ld8(Ab + ks * 32);
#pragma unroll
    for (int nf = 0; nf < 8; ++nf) {
      short8 bv = ld8(Bb + (size_t)nf * 4096 + ks * 32);
      acc[nf] = MFMA16(a0, bv, acc[nf]);
    }
  }
  float bias[4];
#pragma unroll
  for (int reg = 0; reg < 4; ++reg) bias[reg] = bout[o0 + g * 4 + reg];
#pragma unroll
  for (int nf = 0; nf < 8; ++nf)
#pragma unroll
    for (int reg = 0; reg < 4; ++reg) {
      size_t o = (size_t)(b * 256 + o0 + g * 4 + reg);
      out[(o << 10) + w * 128 + nf * 16 + r] = acc[nf][reg] + bias[reg];
    }
}

extern "C" void kernel_launch(void* const* d_in, const int* in_sizes, int n_in,
                              void* d_out, int out_size, void* d_ws, size_t ws_size,
                              hipStream_t stream) {
  const float* x     = (const float*)d_in[0];
  const float* y     = (const float*)d_in[1];
  const float* wqkv  = (const float*)d_in[2];
  const float* wout  = (const float*)d_in[3];
  const float* bout  = (const float*)d_in[4];
  float* out = (float*)d_out;
  char* ws = (char*)d_ws;

  // Aliased workspace (40.5 MB total). Lifetimes:
  //  A: xbt (dead after k_qkv)  -> qt  (written by k_normt)
  //  B: ybt (dead after k_qkv)  -> kt  (written by k_normt)
  //  C: qraw (dead after k_normt) -> aot (written by k_attn)
  ushort* xbt   = (ushort*)(ws + 0ull);          // 8 MiB
  ushort* qt    = (ushort*)(ws + 0ull);
  ushort* ybt   = (ushort*)(ws + 8388608ull);    // 8 MiB
  ushort* kt    = (ushort*)(ws + 8388608ull);
  ushort* qraw  = (ushort*)(ws + 16777216ull);   // 8 MiB
  ushort* aot   = (ushort*)(ws + 16777216ull);
  ushort* kraw  = (ushort*)(ws + 25165824ull);   // 8 MiB
  ushort* vbuf  = (ushort*)(ws + 33554432ull);   // 8 MiB
  ushort* wqkvb = (ushort*)(ws + 41943040ull);   // 384 KiB
  ushort* woutb = (ushort*)(ws + 42336256ull);   // 128 KiB
  float*  norms = (float*) (ws + 42467328ull);   // 32 KiB

  k_tcvt<<<2048, 256, 0, stream>>>(x, y, xbt, ybt);
  k_wcvt<<<256, 256, 0, stream>>>(wqkv, wout, wqkvb, woutb);
  k_qkv<<<dim3(24, 16), 512, 0, stream>>>(wqkvb, xbt, ybt, qraw, kraw, vbuf, norms);
  k_normt<<<2048, 256, 0, stream>>>(qraw, kraw, norms, qt, kt);
  k_attn<<<dim3(8, 4, 16), 256, 0, stream>>>(qt, kt, vbuf, aot);
  k_out<<<dim3(16, 16), 512, 0, stream>>>(woutb, aot, bout, out);
}